// Round 6
// baseline (483.075 us; speedup 1.0000x reference)
//
#include <hip/hip_runtime.h>
#include <hip/hip_bf16.h>

constexpr int Bb = 2, Nn = 2048, Ff = 768, Hh = 8, Oo = 256;

typedef __attribute__((ext_vector_type(8)))  short   short8;
typedef __attribute__((ext_vector_type(16))) float   f32x16;
typedef __attribute__((ext_vector_type(4)))  unsigned short ushort4_t;

__device__ inline unsigned short f2bf(float f) {
    unsigned u = __float_as_uint(f);
    u = (u + 0x7FFFu + ((u >> 16) & 1u)) >> 16;   // RNE
    return (unsigned short)u;
}

// ---------------- adjacency bitmask ----------------
__global__ __launch_bounds__(256) void adjbits_kernel(
        const float* __restrict__ adj, unsigned long long* __restrict__ bits) {
    size_t gid = (size_t)blockIdx.x * 256 + threadIdx.x;
    float v = adj[gid];
    unsigned long long m = __ballot(v > 0.f);
    if ((threadIdx.x & 63) == 0) bits[gid >> 6] = m;
}

// ---------------- f32 -> bf16 flat cast ----------------
__global__ __launch_bounds__(256) void cast_bf_kernel(
        const float* __restrict__ in, unsigned short* __restrict__ out) {
    size_t i = (size_t)blockIdx.x * 256 + threadIdx.x;
    float4 v = ((const float4*)in)[i];
    ushort4_t o;
    o.x = f2bf(v.x); o.y = f2bf(v.y); o.z = f2bf(v.z); o.w = f2bf(v.w);
    ((ushort4_t*)out)[i] = o;
}

// ---------------- [z][R][C] f32 -> [z][C][R] bf16 transpose ----------------
__global__ __launch_bounds__(256) void transpose_bf_kernel(
        const float* __restrict__ in, unsigned short* __restrict__ out, int R, int C) {
    __shared__ float tile[32][33];
    int c0 = blockIdx.x * 32, r0 = blockIdx.y * 32;
    const float* ib = in + (size_t)blockIdx.z * R * C;
    unsigned short* ob = out + (size_t)blockIdx.z * R * C;
    int tx = threadIdx.x & 31, ty = threadIdx.x >> 5;
    for (int k = 0; k < 32; k += 8)
        tile[ty + k][tx] = ib[(size_t)(r0 + ty + k) * C + c0 + tx];
    __syncthreads();
    for (int k = 0; k < 32; k += 8)
        ob[(size_t)(c0 + ty + k) * R + r0 + tx] = f2bf(tile[tx][ty + k]);
}

// ---------------- MFMA GEMM: C[M x 256] = A[M x K] * BT[256 x K]^T ----------------
__global__ __launch_bounds__(256) void gemm_bf_kernel(
        const unsigned short* __restrict__ A, int K, long long sA, int bAshift,
        const unsigned short* __restrict__ BT, long long sB, int bmask,
        float* __restrict__ C, long long sC,
        unsigned short* __restrict__ CT, long long sCT, int Mtot,
        const float* __restrict__ bias, int mode) {
    int z = blockIdx.z;
    A  += (size_t)(z >> bAshift) * sA;
    BT += (size_t)(z & bmask) * sB;
    C  += (size_t)z * sC;
    if (CT) CT += (size_t)z * sCT;
    int m0 = blockIdx.x * 64;
    int t = threadIdx.x;
    int wv = t >> 6, lane = t & 63;
    int lm = lane & 31, kh = lane >> 5;
    __shared__ unsigned short As[64][40];
    f32x16 acc[2][2] = {};
    int sr = t >> 2, sc = (t & 3) * 8;
    const unsigned short* ag  = A + (size_t)(m0 + sr) * K + sc;
    const unsigned short* bg0 = BT + (size_t)(wv * 64 + lm) * K;
    const unsigned short* bg1 = BT + (size_t)(wv * 64 + 32 + lm) * K;
    for (int k0 = 0; k0 < K; k0 += 32) {
        *(short8*)&As[sr][sc] = *(const short8*)(ag + k0);
        __syncthreads();
#pragma unroll
        for (int ks = 0; ks < 32; ks += 16) {
            short8 a0 = *(const short8*)&As[lm][ks + kh * 8];
            short8 a1 = *(const short8*)&As[32 + lm][ks + kh * 8];
            short8 b0 = *(const short8*)(bg0 + k0 + ks + kh * 8);
            short8 b1 = *(const short8*)(bg1 + k0 + ks + kh * 8);
            acc[0][0] = __builtin_amdgcn_mfma_f32_32x32x16_bf16(a0, b0, acc[0][0], 0, 0, 0);
            acc[0][1] = __builtin_amdgcn_mfma_f32_32x32x16_bf16(a0, b1, acc[0][1], 0, 0, 0);
            acc[1][0] = __builtin_amdgcn_mfma_f32_32x32x16_bf16(a1, b0, acc[1][0], 0, 0, 0);
            acc[1][1] = __builtin_amdgcn_mfma_f32_32x32x16_bf16(a1, b1, acc[1][1], 0, 0, 0);
        }
        __syncthreads();
    }
#pragma unroll
    for (int mt = 0; mt < 2; ++mt)
#pragma unroll
        for (int nt = 0; nt < 2; ++nt) {
            int colg = wv * 64 + nt * 32 + lm;
            float bv = (mode == 2) ? bias[colg] : 0.f;
#pragma unroll
            for (int reg = 0; reg < 16; ++reg) {
                int rl = mt * 32 + 4 * kh + (reg & 3) + 8 * (reg >> 2);
                float v = acc[mt][nt][reg];
                if (mode == 2) { v += bv; v = fmaxf(v, 0.f); }
                C[(size_t)(m0 + rl) * 256 + colg] = v;
            }
            if (mode == 1) {
                unsigned short* ctp = CT + (size_t)colg * Mtot + m0 + mt * 32 + 4 * kh;
#pragma unroll
                for (int q = 0; q < 4; ++q) {
                    ushort4_t pk;
                    pk.x = f2bf(acc[mt][nt][q * 4 + 0]);
                    pk.y = f2bf(acc[mt][nt][q * 4 + 1]);
                    pk.z = f2bf(acc[mt][nt][q * 4 + 2]);
                    pk.w = f2bf(acc[mt][nt][q * 4 + 3]);
                    *(ushort4_t*)(ctp + 8 * q) = pk;
                }
            }
        }
}

// ---------------- scores + exp factors ----------------
__global__ __launch_bounds__(256) void scores_exp_kernel(
        const float* __restrict__ h, const float* __restrict__ a,
        float* __restrict__ E1p, float* __restrict__ E1n,
        float2* __restrict__ E2pn, int NperH, int H) {
    int tid = threadIdx.x;
    int lane = tid & 63, wv = tid >> 6;
    long long row = (long long)blockIdx.x * 4 + wv;
    int head = (int)((row / NperH) % H);
    const float* ap = a + (size_t)head * 2 * Oo;
    float4 x4 = ((const float4*)(h + (size_t)row * Oo))[lane];
    float4 a1 = ((const float4*)ap)[lane];
    float4 a2 = ((const float4*)(ap + Oo))[lane];
    float t1 = x4.x * a1.x + x4.y * a1.y + x4.z * a1.z + x4.w * a1.w;
    float t2 = x4.x * a2.x + x4.y * a2.y + x4.z * a2.z + x4.w * a2.w;
    for (int off = 32; off; off >>= 1) {
        t1 += __shfl_down(t1, off, 64);
        t2 += __shfl_down(t2, off, 64);
    }
    if (!lane) {
        E1p[row] = __expf(t1);
        E1n[row] = __expf(0.2f * t1);
        E2pn[row] = make_float2(__expf(t2), __expf(0.2f * t2));
    }
}

// ---------------- pipelined MFMA attention, 32 i-rows/block ----------------
// MODE 0: direct (elu, bf16 out).  MODE 1: partial over j-range (f32 acc + l).
// grid (Nn/32, NBH, NJS). 4 waves; wave covers 32m x 64n (acc[2] of 32x32).
template<int JLEN, int MODE>
__global__ __launch_bounds__(256, 4) void attn_v3_kernel(
        const unsigned short* __restrict__ hT, long long sHT,
        const unsigned* __restrict__ bits,
        const float* __restrict__ E1p, const float* __restrict__ E1n,
        const float2* __restrict__ E2pn,
        unsigned short* __restrict__ outbf, int ldo,
        float* __restrict__ pacc, float* __restrict__ plsum,
        int hshift) {
    constexpr int W = JLEN / 32, NC = JLEN / 64, ABS = W + 1;
    int it = blockIdx.x, bh = blockIdx.y, js = blockIdx.z;
    int b = bh >> hshift, hd = bh & ((1 << hshift) - 1);
    int i0 = it * 32, jbase = js * JLEN;
    int t = threadIdx.x, lane = t & 63;
    int wv = t >> 6, lm = lane & 31, kh = lane >> 5;
    int ti = t & 31, jsub = t >> 5;          // P-compute mapping: 32 rows x 8 j-groups

    __shared__ unsigned ab[32 * ABS];
    __shared__ __align__(16) unsigned short ps[2][32][64];
    __shared__ float lred[32][9];
    __shared__ float linv[32];

    const unsigned* bb = bits + ((size_t)b * Nn + i0) * 64 + (jbase >> 5);
    for (int k = t; k < 32 * W; k += 256) {
        int r = k / W, w0 = k - r * W;
        ab[r * ABS + w0] = bb[(size_t)r * 64 + w0];
    }
    __syncthreads();   // ab[] staged by other threads must be visible before computeP

    float e1p = E1p[(size_t)bh * Nn + i0 + ti];
    float e1n = E1n[(size_t)bh * Nn + i0 + ti];
    const float4* e2base = (const float4*)(E2pn + (size_t)bh * Nn + jbase);

    const unsigned short* hTb = hT + (size_t)bh * sHT + jbase;
    const unsigned short* bg0 = hTb + (size_t)(wv * 64 + lm) * Nn;
    const unsigned short* bg1 = hTb + (size_t)(wv * 64 + 32 + lm) * Nn;

    f32x16 acc[2] = {};
    float lpart = 0.f;
    short8 B0[8], B1[8];

    auto loadB = [&](int c, short8* B) {
#pragma unroll
        for (int s = 0; s < 4; ++s) {
            B[2 * s]     = *(const short8*)(bg0 + c * 64 + s * 16 + kh * 8);
            B[2 * s + 1] = *(const short8*)(bg1 + c * 64 + s * 16 + kh * 8);
        }
    };
    auto computeP = [&](int c, int buf) {
        int cj = c * 64;
        unsigned fld = (ab[ti * ABS + ((cj >> 5) + (jsub >> 2))] >> ((jsub & 3) * 8)) & 0xffu;
        const float4* ep = e2base + ((cj + jsub * 8) >> 1);
        unsigned pk[4];
#pragma unroll
        for (int u = 0; u < 4; ++u) {
            float4 q = ep[u];
            float pp0 = e1p * q.x, pn0 = e1n * q.y;
            float p0 = pp0 > 1.f ? pp0 : pn0;
            p0 = ((fld >> (2 * u)) & 1u) ? p0 : 0.f;
            float pp1 = e1p * q.z, pn1 = e1n * q.w;
            float p1 = pp1 > 1.f ? pp1 : pn1;
            p1 = ((fld >> (2 * u + 1)) & 1u) ? p1 : 0.f;
            lpart += p0 + p1;
            __hip_bfloat162 hv = __float22bfloat162_rn(make_float2(p0, p1));
            pk[u] = *(unsigned*)&hv;
        }
        uint4 v; v.x = pk[0]; v.y = pk[1]; v.z = pk[2]; v.w = pk[3];
        *(uint4*)&ps[buf][ti][(jsub ^ (ti & 7)) * 8] = v;
    };
    auto mfmaStep = [&](int buf, short8* B) {
        unsigned sw = lm & 7;
#pragma unroll
        for (int s = 0; s < 4; ++s) {
            short8 a0 = *(const short8*)&ps[buf][lm][((2 * s + kh) ^ sw) * 8];
            acc[0] = __builtin_amdgcn_mfma_f32_32x32x16_bf16(a0, B[2 * s],     acc[0], 0, 0, 0);
            acc[1] = __builtin_amdgcn_mfma_f32_32x32x16_bf16(a0, B[2 * s + 1], acc[1], 0, 0, 0);
        }
    };

    loadB(0, B0);
    computeP(0, 0);
    __syncthreads();
    for (int c = 0; c < NC; c += 2) {
        loadB(c + 1, B1);
        mfmaStep(0, B0);
        computeP(c + 1, 1);
        __syncthreads();
        if (c + 2 < NC) loadB(c + 2, B0);
        mfmaStep(1, B1);
        if (c + 2 < NC) computeP(c + 2, 0);
        __syncthreads();
    }

    lred[ti][jsub] = lpart;
    __syncthreads();
    if (MODE == 0) {
        if (t < 32) {
            float s = 0.f;
#pragma unroll
            for (int k = 0; k < 8; ++k) s += lred[t][k];
            linv[t] = 1.f / s;
        }
        __syncthreads();
#pragma unroll
        for (int nt = 0; nt < 2; ++nt) {
            int o = wv * 64 + nt * 32 + lm;
#pragma unroll
            for (int reg = 0; reg < 16; ++reg) {
                int rl = 4 * kh + (reg & 3) + 8 * (reg >> 2);
                float v = acc[nt][reg] * linv[rl];
                v = v > 0.f ? v : expm1f(v);   // elu (layer 1)
                outbf[((size_t)b * Nn + i0 + rl) * ldo + (size_t)hd * Oo + o] = f2bf(v);
            }
        }
    } else {
        size_t pidx = (size_t)js * gridDim.y + bh;
        if (t < 32) {
            float s = 0.f;
#pragma unroll
            for (int k = 0; k < 8; ++k) s += lred[t][k];
            plsum[pidx * Nn + i0 + t] = s;
        }
        float* pa = pacc + pidx * Nn * 256;
#pragma unroll
        for (int nt = 0; nt < 2; ++nt) {
            int o = wv * 64 + nt * 32 + lm;
#pragma unroll
            for (int reg = 0; reg < 16; ++reg) {
                int rl = 4 * kh + (reg & 3) + 8 * (reg >> 2);
                pa[(size_t)(i0 + rl) * 256 + o] = acc[nt][reg];
            }
        }
    }
}

// ---------------- combine 8 partials (single-head layer): x2 = Σacc/Σl + lin + b ----------------
__global__ __launch_bounds__(256) void combine8_kernel(
        const float* __restrict__ pacc, const float* __restrict__ plsum,
        const float* __restrict__ lin, const float* __restrict__ bias,
        unsigned short* __restrict__ out) {
    int gid = blockIdx.x * 256 + threadIdx.x;   // per float4; total B*N*64
    int row = gid >> 6;
    int o4 = gid & 63;
    size_t ps4 = (size_t)Bb * Nn * 64;
    const float4* p = (const float4*)pacc + (size_t)row * 64 + o4;
    float4 s = p[0];
#pragma unroll
    for (int k = 1; k < 8; ++k) {
        float4 q = p[k * ps4];
        s.x += q.x; s.y += q.y; s.z += q.z; s.w += q.w;
    }
    int BN = Bb * Nn;
    float lsum = 0.f;
#pragma unroll
    for (int k = 0; k < 8; ++k) lsum += plsum[row + k * BN];
    float li = 1.f / lsum;
    float4 lv = ((const float4*)lin)[(size_t)row * 64 + o4];
    float4 bv = ((const float4*)bias)[o4];
    float4 v;
    v.x = s.x * li + lv.x + bv.x; v.y = s.y * li + lv.y + bv.y;
    v.z = s.z * li + lv.z + bv.z; v.w = s.w * li + lv.w + bv.w;
    __hip_bfloat162 h0 = __float22bfloat162_rn(make_float2(v.x, v.y));
    __hip_bfloat162 h1 = __float22bfloat162_rn(make_float2(v.z, v.w));
    uint2 st; st.x = *(unsigned*)&h0; st.y = *(unsigned*)&h1;
    *(uint2*)(out + (size_t)gid * 4) = st;
}

extern "C" void kernel_launch(void* const* d_in, const int* in_sizes, int n_in,
                              void* d_out, int out_size, void* d_ws, size_t ws_size,
                              hipStream_t stream) {
    const float* x       = (const float*)d_in[0];
    const float* adj     = (const float*)d_in[1];
    const float* W_heads = (const float*)d_in[3];
    const float* a_heads = (const float*)d_in[4];
    const float* W_out   = (const float*)d_in[5];
    const float* a_out   = (const float*)d_in[6];
    const float* W_lin   = (const float*)d_in[7];
    const float* b_lin   = (const float*)d_in[8];
    const float* W_ln    = (const float*)d_in[9];
    const float* b_ln    = (const float*)d_in[10];

    char* w = (char*)d_ws;   // ~90.9 MB
    float* h        = (float*)(w);                    // [16][2048][256] f32 (dead after scores_mh; reused for sh partials)
    float* lin      = (float*)(w + 33554432);         // [2][2048][256]
    float* h2       = (float*)(w + 37748736);         // [2][2048][256]
    float* E1p_mh   = (float*)(w + 41943040);
    float* E1n_mh   = (float*)(w + 42074112);
    float2* E2pn_mh = (float2*)(w + 42205184);
    float* E1p_sh   = (float*)(w + 42467328);
    float* E1n_sh   = (float*)(w + 42483712);
    float2* E2pn_sh = (float2*)(w + 42500096);
    unsigned long long* bits = (unsigned long long*)(w + 42532864);   // 1 MB
    unsigned short* x_bf  = (unsigned short*)(w + 43581440);   // [2][2048][768] (dead after gemm1)
    unsigned short* x2_bf = (unsigned short*)(w + 43581440);   // reuse x_bf region
    unsigned short* WhT   = (unsigned short*)(w + 49872896);   // [8][256][768]
    unsigned short* WoT   = (unsigned short*)(w + 53018624);   // [256][2048]
    unsigned short* Wl_bf = (unsigned short*)(w + 54067200);   // [256][2048]
    unsigned short* Wn_bf = (unsigned short*)(w + 55115776);   // [256][256]
    unsigned short* hT    = (unsigned short*)(w + 55246848);   // [16][256][2048]
    unsigned short* h2T   = (unsigned short*)(w + 72024064);   // [2][256][2048]
    unsigned short* x1_bf = (unsigned short*)(w + 74121216);   // [2][2048][2048]
    float* pacc  = h;                                          // 8x[2][2048][256] f32 = 33.5 MB (== h region)
    float* plsum = E1p_mh;                                     // 8x[2][2048] f32 = 128 KB (E_mh dead by then)

    // 0) prep
    adjbits_kernel<<<(Bb * Nn * Nn) / 256, 256, 0, stream>>>(adj, bits);
    cast_bf_kernel<<<(Bb * Nn * Ff) / 1024, 256, 0, stream>>>(x, x_bf);
    cast_bf_kernel<<<(Oo * Hh * Oo) / 1024, 256, 0, stream>>>(W_lin, Wl_bf);
    cast_bf_kernel<<<(Oo * Oo) / 1024, 256, 0, stream>>>(W_ln, Wn_bf);
    transpose_bf_kernel<<<dim3(Oo / 32, Ff / 32, Hh), 256, 0, stream>>>(W_heads, WhT, Ff, Oo);
    transpose_bf_kernel<<<dim3(Oo / 32, (Hh * Oo) / 32, 1), 256, 0, stream>>>(W_out, WoT, Hh * Oo, Oo);

    // 1) h = x @ W_heads (+ hT bf16)
    gemm_bf_kernel<<<dim3(Nn / 64, 1, Bb * Hh), 256, 0, stream>>>(
        x_bf, Ff, (long long)Nn * Ff, 3, WhT, (long long)Ff * Oo, 7,
        h, (long long)Nn * Oo, hT, (long long)Nn * Oo, Nn, nullptr, 1);
    // 2) scores + exp factors (mh)
    scores_exp_kernel<<<(Bb * Hh * Nn) / 4, 256, 0, stream>>>(h, a_heads, E1p_mh, E1n_mh, E2pn_mh, Nn, Hh);
    // 3) multihead attention + elu -> x1_bf  (32-row tiles, 1024 blocks)
    attn_v3_kernel<2048, 0><<<dim3(Nn / 32, Bb * Hh, 1), 256, 0, stream>>>(
        hT, (long long)Oo * Nn, (const unsigned*)bits, E1p_mh, E1n_mh, E2pn_mh,
        x1_bf, Hh * Oo, nullptr, nullptr, 3);
    // 4) h2 = x1 @ W_out (+ h2T bf16)
    gemm_bf_kernel<<<dim3(Nn / 64, 1, Bb), 256, 0, stream>>>(
        x1_bf, Hh * Oo, (long long)Nn * Hh * Oo, 0, WoT, 0, 0,
        h2, (long long)Nn * Oo, h2T, (long long)Nn * Oo, Nn, nullptr, 1);
    // 5) lin = x1 @ W_lin^T
    gemm_bf_kernel<<<dim3(Nn / 64, 1, Bb), 256, 0, stream>>>(
        x1_bf, Hh * Oo, (long long)Nn * Hh * Oo, 0, Wl_bf, 0, 0,
        lin, (long long)Nn * Oo, nullptr, 0, Nn, nullptr, 0);
    // 6) scores + exp factors (sh)
    scores_exp_kernel<<<(Bb * Nn) / 4, 256, 0, stream>>>(h2, a_out, E1p_sh, E1n_sh, E2pn_sh, Nn, 1);
    // 7) single-head attention, 8-way j-split partials (32-row tiles, 1024 blocks)
    attn_v3_kernel<256, 1><<<dim3(Nn / 32, Bb, 8), 256, 0, stream>>>(
        h2T, (long long)Oo * Nn, (const unsigned*)bits, E1p_sh, E1n_sh, E2pn_sh,
        nullptr, 0, pacc, plsum, 0);
    // 8) combine -> x2_bf
    combine8_kernel<<<(Bb * Nn * 64) / 256, 256, 0, stream>>>(pacc, plsum, lin, b_lin, x2_bf);
    // 9) out = relu(x2 @ W_ln^T + b_ln)
    gemm_bf_kernel<<<dim3(Nn / 64, 1, Bb), 256, 0, stream>>>(
        x2_bf, Oo, (long long)Nn * Oo, 0, Wn_bf, 0, 0,
        (float*)d_out, (long long)Nn * Oo, nullptr, 0, Nn, b_ln, 2);
}

// Round 7
// 366.809 us; speedup vs baseline: 1.3170x; 1.3170x over previous
//
#include <hip/hip_runtime.h>
#include <hip/hip_bf16.h>

constexpr int Bb = 2, Nn = 2048, Ff = 768, Hh = 8, Oo = 256;

typedef __attribute__((ext_vector_type(8)))  short   short8;
typedef __attribute__((ext_vector_type(16))) float   f32x16;
typedef __attribute__((ext_vector_type(4)))  unsigned short ushort4_t;

__device__ inline unsigned short f2bf(float f) {
    unsigned u = __float_as_uint(f);
    u = (u + 0x7FFFu + ((u >> 16) & 1u)) >> 16;   // RNE
    return (unsigned short)u;
}

// ---------------- adjacency bitmask ----------------
__global__ __launch_bounds__(256) void adjbits_kernel(
        const float* __restrict__ adj, unsigned long long* __restrict__ bits) {
    size_t gid = (size_t)blockIdx.x * 256 + threadIdx.x;
    float v = adj[gid];
    unsigned long long m = __ballot(v > 0.f);
    if ((threadIdx.x & 63) == 0) bits[gid >> 6] = m;
}

// ---------------- f32 -> bf16 flat cast ----------------
__global__ __launch_bounds__(256) void cast_bf_kernel(
        const float* __restrict__ in, unsigned short* __restrict__ out) {
    size_t i = (size_t)blockIdx.x * 256 + threadIdx.x;
    float4 v = ((const float4*)in)[i];
    ushort4_t o;
    o.x = f2bf(v.x); o.y = f2bf(v.y); o.z = f2bf(v.z); o.w = f2bf(v.w);
    ((ushort4_t*)out)[i] = o;
}

// ---------------- [z][R][C] f32 -> [z][C][R] bf16 transpose ----------------
__global__ __launch_bounds__(256) void transpose_bf_kernel(
        const float* __restrict__ in, unsigned short* __restrict__ out, int R, int C) {
    __shared__ float tile[32][33];
    int c0 = blockIdx.x * 32, r0 = blockIdx.y * 32;
    const float* ib = in + (size_t)blockIdx.z * R * C;
    unsigned short* ob = out + (size_t)blockIdx.z * R * C;
    int tx = threadIdx.x & 31, ty = threadIdx.x >> 5;
    for (int k = 0; k < 32; k += 8)
        tile[ty + k][tx] = ib[(size_t)(r0 + ty + k) * C + c0 + tx];
    __syncthreads();
    for (int k = 0; k < 32; k += 8)
        ob[(size_t)(c0 + ty + k) * R + r0 + tx] = f2bf(tile[tx][ty + k]);
}

// ---------------- MFMA GEMM: C[M x 256] = A[M x K] * BT[256 x K]^T ----------------
__global__ __launch_bounds__(256) void gemm_bf_kernel(
        const unsigned short* __restrict__ A, int K, long long sA, int bAshift,
        const unsigned short* __restrict__ BT, long long sB, int bmask,
        float* __restrict__ C, long long sC,
        unsigned short* __restrict__ CT, long long sCT, int Mtot,
        const float* __restrict__ bias, int mode) {
    int z = blockIdx.z;
    A  += (size_t)(z >> bAshift) * sA;
    BT += (size_t)(z & bmask) * sB;
    C  += (size_t)z * sC;
    if (CT) CT += (size_t)z * sCT;
    int m0 = blockIdx.x * 64;
    int t = threadIdx.x;
    int wv = t >> 6, lane = t & 63;
    int lm = lane & 31, kh = lane >> 5;
    __shared__ unsigned short As[64][40];
    f32x16 acc[2][2] = {};
    int sr = t >> 2, sc = (t & 3) * 8;
    const unsigned short* ag  = A + (size_t)(m0 + sr) * K + sc;
    const unsigned short* bg0 = BT + (size_t)(wv * 64 + lm) * K;
    const unsigned short* bg1 = BT + (size_t)(wv * 64 + 32 + lm) * K;
    for (int k0 = 0; k0 < K; k0 += 32) {
        *(short8*)&As[sr][sc] = *(const short8*)(ag + k0);
        __syncthreads();
#pragma unroll
        for (int ks = 0; ks < 32; ks += 16) {
            short8 a0 = *(const short8*)&As[lm][ks + kh * 8];
            short8 a1 = *(const short8*)&As[32 + lm][ks + kh * 8];
            short8 b0 = *(const short8*)(bg0 + k0 + ks + kh * 8);
            short8 b1 = *(const short8*)(bg1 + k0 + ks + kh * 8);
            acc[0][0] = __builtin_amdgcn_mfma_f32_32x32x16_bf16(a0, b0, acc[0][0], 0, 0, 0);
            acc[0][1] = __builtin_amdgcn_mfma_f32_32x32x16_bf16(a0, b1, acc[0][1], 0, 0, 0);
            acc[1][0] = __builtin_amdgcn_mfma_f32_32x32x16_bf16(a1, b0, acc[1][0], 0, 0, 0);
            acc[1][1] = __builtin_amdgcn_mfma_f32_32x32x16_bf16(a1, b1, acc[1][1], 0, 0, 0);
        }
        __syncthreads();
    }
#pragma unroll
    for (int mt = 0; mt < 2; ++mt)
#pragma unroll
        for (int nt = 0; nt < 2; ++nt) {
            int colg = wv * 64 + nt * 32 + lm;
            float bv = (mode == 2) ? bias[colg] : 0.f;
#pragma unroll
            for (int reg = 0; reg < 16; ++reg) {
                int rl = mt * 32 + 4 * kh + (reg & 3) + 8 * (reg >> 2);
                float v = acc[mt][nt][reg];
                if (mode == 2) { v += bv; v = fmaxf(v, 0.f); }
                C[(size_t)(m0 + rl) * 256 + colg] = v;
            }
            if (mode == 1) {
                unsigned short* ctp = CT + (size_t)colg * Mtot + m0 + mt * 32 + 4 * kh;
#pragma unroll
                for (int q = 0; q < 4; ++q) {
                    ushort4_t pk;
                    pk.x = f2bf(acc[mt][nt][q * 4 + 0]);
                    pk.y = f2bf(acc[mt][nt][q * 4 + 1]);
                    pk.z = f2bf(acc[mt][nt][q * 4 + 2]);
                    pk.w = f2bf(acc[mt][nt][q * 4 + 3]);
                    *(ushort4_t*)(ctp + 8 * q) = pk;
                }
            }
        }
}

// ---------------- dual MFMA GEMM: x1 @ [WoT ; Wl]^T in one launch ----------------
// grid (M/64, 2, B). ng==0 -> h2 f32 + h2T bf16 ; ng==1 -> lin f32.
__global__ __launch_bounds__(256) void gemm_dual_kernel(
        const unsigned short* __restrict__ A, int K, long long sA,
        const unsigned short* __restrict__ BT,
        float* __restrict__ h2, unsigned short* __restrict__ h2T,
        float* __restrict__ lin) {
    int b = blockIdx.z, ng = blockIdx.y;
    A += (size_t)b * sA;
    BT += (size_t)ng * 256 * K;
    int m0 = blockIdx.x * 64;
    int t = threadIdx.x;
    int wv = t >> 6, lane = t & 63;
    int lm = lane & 31, kh = lane >> 5;
    __shared__ unsigned short As[64][40];
    f32x16 acc[2][2] = {};
    int sr = t >> 2, sc = (t & 3) * 8;
    const unsigned short* ag  = A + (size_t)(m0 + sr) * K + sc;
    const unsigned short* bg0 = BT + (size_t)(wv * 64 + lm) * K;
    const unsigned short* bg1 = BT + (size_t)(wv * 64 + 32 + lm) * K;
    for (int k0 = 0; k0 < K; k0 += 32) {
        *(short8*)&As[sr][sc] = *(const short8*)(ag + k0);
        __syncthreads();
#pragma unroll
        for (int ks = 0; ks < 32; ks += 16) {
            short8 a0 = *(const short8*)&As[lm][ks + kh * 8];
            short8 a1 = *(const short8*)&As[32 + lm][ks + kh * 8];
            short8 b0 = *(const short8*)(bg0 + k0 + ks + kh * 8);
            short8 b1 = *(const short8*)(bg1 + k0 + ks + kh * 8);
            acc[0][0] = __builtin_amdgcn_mfma_f32_32x32x16_bf16(a0, b0, acc[0][0], 0, 0, 0);
            acc[0][1] = __builtin_amdgcn_mfma_f32_32x32x16_bf16(a0, b1, acc[0][1], 0, 0, 0);
            acc[1][0] = __builtin_amdgcn_mfma_f32_32x32x16_bf16(a1, b0, acc[1][0], 0, 0, 0);
            acc[1][1] = __builtin_amdgcn_mfma_f32_32x32x16_bf16(a1, b1, acc[1][1], 0, 0, 0);
        }
        __syncthreads();
    }
    float* C = (ng == 0 ? h2 : lin) + (size_t)b * Nn * 256;
#pragma unroll
    for (int mt = 0; mt < 2; ++mt)
#pragma unroll
        for (int nt = 0; nt < 2; ++nt) {
            int colg = wv * 64 + nt * 32 + lm;
#pragma unroll
            for (int reg = 0; reg < 16; ++reg) {
                int rl = mt * 32 + 4 * kh + (reg & 3) + 8 * (reg >> 2);
                C[(size_t)(m0 + rl) * 256 + colg] = acc[mt][nt][reg];
            }
            if (ng == 0) {
                unsigned short* ctp = h2T + (size_t)b * Nn * 256 +
                                      (size_t)colg * Nn + m0 + mt * 32 + 4 * kh;
#pragma unroll
                for (int q = 0; q < 4; ++q) {
                    ushort4_t pk;
                    pk.x = f2bf(acc[mt][nt][q * 4 + 0]);
                    pk.y = f2bf(acc[mt][nt][q * 4 + 1]);
                    pk.z = f2bf(acc[mt][nt][q * 4 + 2]);
                    pk.w = f2bf(acc[mt][nt][q * 4 + 3]);
                    *(ushort4_t*)(ctp + 8 * q) = pk;
                }
            }
        }
}

// ---------------- scores + exp factors ----------------
__global__ __launch_bounds__(256) void scores_exp_kernel(
        const float* __restrict__ h, const float* __restrict__ a,
        float* __restrict__ E1p, float* __restrict__ E1n,
        float2* __restrict__ E2pn, int NperH, int H) {
    int tid = threadIdx.x;
    int lane = tid & 63, wv = tid >> 6;
    long long row = (long long)blockIdx.x * 4 + wv;
    int head = (int)((row / NperH) % H);
    const float* ap = a + (size_t)head * 2 * Oo;
    float4 x4 = ((const float4*)(h + (size_t)row * Oo))[lane];
    float4 a1 = ((const float4*)ap)[lane];
    float4 a2 = ((const float4*)(ap + Oo))[lane];
    float t1 = x4.x * a1.x + x4.y * a1.y + x4.z * a1.z + x4.w * a1.w;
    float t2 = x4.x * a2.x + x4.y * a2.y + x4.z * a2.z + x4.w * a2.w;
    for (int off = 32; off; off >>= 1) {
        t1 += __shfl_down(t1, off, 64);
        t2 += __shfl_down(t2, off, 64);
    }
    if (!lane) {
        E1p[row] = __expf(t1);
        E1n[row] = __expf(0.2f * t1);
        E2pn[row] = make_float2(__expf(t2), __expf(0.2f * t2));
    }
}

// ---------------- pipelined MFMA attention, 64 i-rows/block ----------------
// MODE 0: direct (elu, bf16 out).  MODE 1: partial over j-range (f32 acc + l).
// SWAPXY 1: blockIdx.x = bh (XCD-pins each head: XCD = bh % 8), blockIdx.y = it.
template<int JLEN, int MODE, int SWAPXY>
__global__ __launch_bounds__(256, 2) void attn_v2_kernel(
        const unsigned short* __restrict__ hT, long long sHT,
        const unsigned* __restrict__ bits,
        const float* __restrict__ E1p, const float* __restrict__ E1n,
        const float2* __restrict__ E2pn,
        unsigned short* __restrict__ outbf, int ldo,
        float* __restrict__ pacc, float* __restrict__ plsum,
        int hshift) {
    constexpr int W = JLEN / 32, NC = JLEN / 64, ABS = W + 1;
    int it = SWAPXY ? blockIdx.y : blockIdx.x;
    int bh = SWAPXY ? blockIdx.x : blockIdx.y;
    int js = blockIdx.z;
    int b = bh >> hshift, hd = bh & ((1 << hshift) - 1);
    int i0 = it * 64, jbase = js * JLEN;
    int t = threadIdx.x, lane = t & 63;
    int wv = t >> 6, lm = lane & 31, kh = lane >> 5;
    int ti = lane, jq = wv;

    __shared__ unsigned ab[64 * ABS];
    __shared__ __align__(16) unsigned short ps[2][64][64];
    __shared__ float lred[64][5];
    __shared__ float linv[64];

    const unsigned* bb = bits + ((size_t)b * Nn + i0) * 64 + (jbase >> 5);
    for (int k = t; k < 64 * W; k += 256) {
        int r = k / W, w0 = k - r * W;
        ab[r * ABS + w0] = bb[(size_t)r * 64 + w0];
    }
    __syncthreads();   // ab[] staged by other threads must be visible before computeP

    float e1p = E1p[(size_t)bh * Nn + i0 + ti];
    float e1n = E1n[(size_t)bh * Nn + i0 + ti];
    const float4* e2base = (const float4*)(E2pn + (size_t)bh * Nn + jbase);

    const unsigned short* hTb = hT + (size_t)bh * sHT + jbase;
    const unsigned short* bg0 = hTb + (size_t)(wv * 64 + lm) * Nn;
    const unsigned short* bg1 = hTb + (size_t)(wv * 64 + 32 + lm) * Nn;

    f32x16 acc[2][2] = {};
    float lpart = 0.f;
    short8 B0[8], B1[8];

    auto loadB = [&](int c, short8* B) {
#pragma unroll
        for (int s = 0; s < 4; ++s) {
            B[2 * s]     = *(const short8*)(bg0 + c * 64 + s * 16 + kh * 8);
            B[2 * s + 1] = *(const short8*)(bg1 + c * 64 + s * 16 + kh * 8);
        }
    };
    auto computeP = [&](int c, int buf) {
        int cj = c * 64;
        unsigned word = ab[ti * ABS + ((cj >> 5) + (jq >> 1))];
        unsigned field = word >> ((jq & 1) * 16);
        const float4* ep = e2base + ((cj + jq * 16) >> 1);
        unsigned pk[8];
#pragma unroll
        for (int u = 0; u < 8; ++u) {
            float4 q = ep[u];
            float pp0 = e1p * q.x, pn0 = e1n * q.y;
            float p0 = pp0 > 1.f ? pp0 : pn0;
            p0 = ((field >> (2 * u)) & 1u) ? p0 : 0.f;
            float pp1 = e1p * q.z, pn1 = e1n * q.w;
            float p1 = pp1 > 1.f ? pp1 : pn1;
            p1 = ((field >> (2 * u + 1)) & 1u) ? p1 : 0.f;
            lpart += p0 + p1;
            __hip_bfloat162 hv = __float22bfloat162_rn(make_float2(p0, p1));
            pk[u] = *(unsigned*)&hv;
        }
        unsigned sw = ti & 7;
        uint4 v0; v0.x = pk[0]; v0.y = pk[1]; v0.z = pk[2]; v0.w = pk[3];
        uint4 v1; v1.x = pk[4]; v1.y = pk[5]; v1.z = pk[6]; v1.w = pk[7];
        *(uint4*)&ps[buf][ti][((2 * jq) ^ sw) * 8]     = v0;
        *(uint4*)&ps[buf][ti][((2 * jq + 1) ^ sw) * 8] = v1;
    };
    auto mfmaStep = [&](int buf, short8* B) {
        unsigned sw = lm & 7;
#pragma unroll
        for (int s = 0; s < 4; ++s) {
            short8 a0 = *(const short8*)&ps[buf][lm][((2 * s + kh) ^ sw) * 8];
            short8 a1 = *(const short8*)&ps[buf][32 + lm][((2 * s + kh) ^ sw) * 8];
            acc[0][0] = __builtin_amdgcn_mfma_f32_32x32x16_bf16(a0, B[2 * s],     acc[0][0], 0, 0, 0);
            acc[0][1] = __builtin_amdgcn_mfma_f32_32x32x16_bf16(a0, B[2 * s + 1], acc[0][1], 0, 0, 0);
            acc[1][0] = __builtin_amdgcn_mfma_f32_32x32x16_bf16(a1, B[2 * s],     acc[1][0], 0, 0, 0);
            acc[1][1] = __builtin_amdgcn_mfma_f32_32x32x16_bf16(a1, B[2 * s + 1], acc[1][1], 0, 0, 0);
        }
    };

    loadB(0, B0);
    computeP(0, 0);
    __syncthreads();
    for (int c = 0; c < NC; c += 2) {
        loadB(c + 1, B1);
        mfmaStep(0, B0);
        computeP(c + 1, 1);
        __syncthreads();
        if (c + 2 < NC) loadB(c + 2, B0);
        mfmaStep(1, B1);
        if (c + 2 < NC) computeP(c + 2, 0);
        __syncthreads();
    }

    lred[ti][jq] = lpart;
    __syncthreads();
    if (MODE == 0) {
        if (t < 64) linv[t] = 1.f / (lred[t][0] + lred[t][1] + lred[t][2] + lred[t][3]);
        __syncthreads();
#pragma unroll
        for (int mt = 0; mt < 2; ++mt)
#pragma unroll
            for (int nt = 0; nt < 2; ++nt) {
                int o = wv * 64 + nt * 32 + lm;
#pragma unroll
                for (int reg = 0; reg < 16; ++reg) {
                    int rl = mt * 32 + 4 * kh + (reg & 3) + 8 * (reg >> 2);
                    float v = acc[mt][nt][reg] * linv[rl];
                    v = v > 0.f ? v : expm1f(v);   // elu (layer 1)
                    outbf[((size_t)b * Nn + i0 + rl) * ldo + (size_t)hd * Oo + o] = f2bf(v);
                }
            }
    } else {
        if (t < 64)
            plsum[((size_t)js * Bb + b) * Nn + i0 + t] =
                lred[t][0] + lred[t][1] + lred[t][2] + lred[t][3];
        float* pa = pacc + (((size_t)js * Bb + b) * Nn) * 256;
#pragma unroll
        for (int mt = 0; mt < 2; ++mt)
#pragma unroll
            for (int nt = 0; nt < 2; ++nt) {
                int o = wv * 64 + nt * 32 + lm;
#pragma unroll
                for (int reg = 0; reg < 16; ++reg) {
                    int rl = mt * 32 + 4 * kh + (reg & 3) + 8 * (reg >> 2);
                    pa[(size_t)(i0 + rl) * 256 + o] = acc[mt][nt][reg];
                }
            }
    }
}

// ---------------- combine partials (single-head layer): x2 = Σacc/Σl + lin + b ----------------
__global__ __launch_bounds__(256) void combine_kernel(
        const float* __restrict__ pacc, const float* __restrict__ plsum,
        const float* __restrict__ lin, const float* __restrict__ bias,
        unsigned short* __restrict__ out) {
    int gid = blockIdx.x * 256 + threadIdx.x;   // per float4; total B*N*64
    int row = gid >> 6;
    int o4 = gid & 63;
    size_t ps4 = (size_t)Bb * Nn * 64;
    const float4* p = (const float4*)pacc + (size_t)row * 64 + o4;
    float4 s = p[0], sa = p[ps4], sb = p[2 * ps4], sc = p[3 * ps4];
    s.x += sa.x + sb.x + sc.x; s.y += sa.y + sb.y + sc.y;
    s.z += sa.z + sb.z + sc.z; s.w += sa.w + sb.w + sc.w;
    int BN = Bb * Nn;
    float li = 1.f / (plsum[row] + plsum[row + BN] + plsum[row + 2 * BN] + plsum[row + 3 * BN]);
    float4 lv = ((const float4*)lin)[(size_t)row * 64 + o4];
    float4 bv = ((const float4*)bias)[o4];
    float4 v;
    v.x = s.x * li + lv.x + bv.x; v.y = s.y * li + lv.y + bv.y;
    v.z = s.z * li + lv.z + bv.z; v.w = s.w * li + lv.w + bv.w;
    __hip_bfloat162 h0 = __float22bfloat162_rn(make_float2(v.x, v.y));
    __hip_bfloat162 h1 = __float22bfloat162_rn(make_float2(v.z, v.w));
    uint2 st; st.x = *(unsigned*)&h0; st.y = *(unsigned*)&h1;
    *(uint2*)(out + (size_t)gid * 4) = st;
}

extern "C" void kernel_launch(void* const* d_in, const int* in_sizes, int n_in,
                              void* d_out, int out_size, void* d_ws, size_t ws_size,
                              hipStream_t stream) {
    const float* x       = (const float*)d_in[0];
    const float* adj     = (const float*)d_in[1];
    const float* W_heads = (const float*)d_in[3];
    const float* a_heads = (const float*)d_in[4];
    const float* W_out   = (const float*)d_in[5];
    const float* a_out   = (const float*)d_in[6];
    const float* W_lin   = (const float*)d_in[7];
    const float* b_lin   = (const float*)d_in[8];
    const float* W_ln    = (const float*)d_in[9];
    const float* b_ln    = (const float*)d_in[10];

    char* w = (char*)d_ws;   // ~90.9 MB
    float* h        = (float*)(w);                    // [16][2048][256] f32 (dead after scores_mh; reused for sh partials)
    float* lin      = (float*)(w + 33554432);         // [2][2048][256]
    float* h2       = (float*)(w + 37748736);         // [2][2048][256]
    float* E1p_mh   = (float*)(w + 41943040);
    float* E1n_mh   = (float*)(w + 42074112);
    float2* E2pn_mh = (float2*)(w + 42205184);
    float* E1p_sh   = (float*)(w + 42467328);
    float* E1n_sh   = (float*)(w + 42483712);
    float2* E2pn_sh = (float2*)(w + 42500096);
    unsigned long long* bits = (unsigned long long*)(w + 42532864);   // 1 MB
    unsigned short* x_bf  = (unsigned short*)(w + 43581440);   // [2][2048][768] (dead after gemm1)
    unsigned short* x2_bf = (unsigned short*)(w + 43581440);   // reuse x_bf region
    unsigned short* WhT   = (unsigned short*)(w + 49872896);   // [8][256][768]
    unsigned short* WoT   = (unsigned short*)(w + 53018624);   // [256][2048]  } adjacent =>
    unsigned short* Wl_bf = (unsigned short*)(w + 54067200);   // [256][2048]  } one [512][2048]
    unsigned short* Wn_bf = (unsigned short*)(w + 55115776);   // [256][256]
    unsigned short* hT    = (unsigned short*)(w + 55246848);   // [16][256][2048]
    unsigned short* h2T   = (unsigned short*)(w + 72024064);   // [2][256][2048]
    unsigned short* x1_bf = (unsigned short*)(w + 74121216);   // [2][2048][2048]
    float* pacc  = h;                                          // 4x[2][2048][256] f32 = 16 MB
    float* plsum = h + 4194304;                                // 4x[2][2048]

    // 0) prep
    adjbits_kernel<<<(Bb * Nn * Nn) / 256, 256, 0, stream>>>(adj, bits);
    cast_bf_kernel<<<(Bb * Nn * Ff) / 1024, 256, 0, stream>>>(x, x_bf);
    cast_bf_kernel<<<(Oo * Hh * Oo) / 1024, 256, 0, stream>>>(W_lin, Wl_bf);
    cast_bf_kernel<<<(Oo * Oo) / 1024, 256, 0, stream>>>(W_ln, Wn_bf);
    transpose_bf_kernel<<<dim3(Oo / 32, Ff / 32, Hh), 256, 0, stream>>>(W_heads, WhT, Ff, Oo);
    transpose_bf_kernel<<<dim3(Oo / 32, (Hh * Oo) / 32, 1), 256, 0, stream>>>(W_out, WoT, Hh * Oo, Oo);

    // 1) h = x @ W_heads (+ hT bf16)
    gemm_bf_kernel<<<dim3(Nn / 64, 1, Bb * Hh), 256, 0, stream>>>(
        x_bf, Ff, (long long)Nn * Ff, 3, WhT, (long long)Ff * Oo, 7,
        h, (long long)Nn * Oo, hT, (long long)Nn * Oo, Nn, nullptr, 1);
    // 2) scores + exp factors (mh)
    scores_exp_kernel<<<(Bb * Hh * Nn) / 4, 256, 0, stream>>>(h, a_heads, E1p_mh, E1n_mh, E2pn_mh, Nn, Hh);
    // 3) multihead attention + elu -> x1_bf  (grid x = bh -> XCD = bh % 8: L2-pins hT slices)
    attn_v2_kernel<2048, 0, 1><<<dim3(Bb * Hh, Nn / 64, 1), 256, 0, stream>>>(
        hT, (long long)Oo * Nn, (const unsigned*)bits, E1p_mh, E1n_mh, E2pn_mh,
        x1_bf, Hh * Oo, nullptr, nullptr, 3);
    // 4+5) fused: h2 = x1 @ W_out (+ h2T bf16) and lin = x1 @ W_lin^T
    gemm_dual_kernel<<<dim3(Nn / 64, 2, Bb), 256, 0, stream>>>(
        x1_bf, Hh * Oo, (long long)Nn * Hh * Oo, WoT, h2, h2T, lin);
    // 6) scores + exp factors (sh)
    scores_exp_kernel<<<(Bb * Nn) / 4, 256, 0, stream>>>(h2, a_out, E1p_sh, E1n_sh, E2pn_sh, Nn, 1);
    // 7) single-head attention, 4-way j-split partials
    attn_v2_kernel<512, 1, 0><<<dim3(Nn / 64, Bb, 4), 256, 0, stream>>>(
        h2T, (long long)Oo * Nn, (const unsigned*)bits, E1p_sh, E1n_sh, E2pn_sh,
        nullptr, 0, pacc, plsum, 0);
    // 8) combine -> x2_bf
    combine_kernel<<<(Bb * Nn * 64) / 256, 256, 0, stream>>>(pacc, plsum, lin, b_lin, x2_bf);
    // 9) out = relu(x2 @ W_ln^T + b_ln)
    gemm_bf_kernel<<<dim3(Nn / 64, 1, Bb), 256, 0, stream>>>(
        x2_bf, Oo, (long long)Nn * Oo, 0, Wn_bf, 0, 0,
        (float*)d_out, (long long)Nn * Oo, nullptr, 0, Nn, b_ln, 2);
}